// Round 3
// baseline (296.791 us; speedup 1.0000x reference)
//
#include <hip/hip_runtime.h>
#include <math.h>

#define EPS_COS 1e-8f
#define EPS_ADD 1e-12f

constexpr int NN = 4096;   // N
constexpr int MM = 64;     // M
constexpr int BLOCK = 256;

using f32x4 = __attribute__((ext_vector_type(4))) float;

__device__ __forceinline__ float block_reduce_sum(float v, float* red) {
    #pragma unroll
    for (int o = 32; o > 0; o >>= 1) v += __shfl_xor(v, o, 64);
    const int wv = threadIdx.x >> 6;
    if ((threadIdx.x & 63) == 0) red[wv] = v;
    __syncthreads();
    float r = (red[0] + red[1]) + (red[2] + red[3]);
    __syncthreads();
    return r;
}

__global__ __launch_bounds__(BLOCK, 4) void ntm_fused(
    const float* __restrict__ beta,
    const float* __restrict__ kappa,
    const float* __restrict__ gamma_p,
    const float* __restrict__ g_p,
    const float* __restrict__ s_p,
    const float* __restrict__ w_prev,
    const float* __restrict__ memory,
    float* __restrict__ out,
    int S)
{
    const int b   = blockIdx.x;
    const int tid = threadIdx.x;
    const int sub = tid & 3;   // 4 threads per row, 16 floats each
    const int row = tid >> 2;  // 64 rows per sweep

    __shared__ float sc[NN];   // e = exp(beta*cos)
    __shared__ float red[4];

    // ---- early prefetch: w_prev fragment (consumed only after the stream) ----
    const float* wpb = w_prev + (size_t)b * NN;
    f32x4 wpv[4]; float wpl[4], wpr[4];
    #pragma unroll
    for (int k = 0; k < 4; ++k) {
        const int idx  = tid + k * BLOCK;
        const int base = 4 * idx;
        wpv[k] = ((const f32x4*)wpb)[idx];
        wpl[k] = wpb[(base + NN - 1) & (NN - 1)];
        wpr[k] = wpb[(base + 4) & (NN - 1)];
    }

    const float beta_b  = beta[b];
    const float g_b     = g_p[b];
    const float gamma_b = gamma_p[b];
    float sreg[8];
    #pragma unroll
    for (int j = 0; j < 8; ++j) sreg[j] = (j < S) ? s_p[(size_t)b * S + j] : 0.0f;

    // kappa fragment: 16 floats at element sub*16 (+eps), and k-norm
    const f32x4* kv = (const f32x4*)(kappa + (size_t)b * MM);
    f32x4 kf[4];
    float ksq = 0.f;
    #pragma unroll
    for (int j = 0; j < 4; ++j) {
        f32x4 t = kv[sub * 4 + j];
        t += EPS_ADD;
        kf[j] = t;
        ksq += t.x * t.x + t.y * t.y + t.z * t.z + t.w * t.w;
    }
    ksq += __shfl_xor(ksq, 1, 64);
    ksq += __shfl_xor(ksq, 2, 64);
    const float knorm = fmaxf(sqrtf(ksq), EPS_COS);
    const float binv  = beta_b / knorm;

    // ---- phase 1: e = exp(beta*cos) into LDS, accumulate softmax denom.
    // |beta*cos| < 1 so no max-subtraction is needed (no overflow possible).
    float lsum = 0.f;
    const f32x4* memv = (const f32x4*)(memory + (size_t)b * NN * MM);
    #pragma unroll 2
    for (int it = 0; it < NN / 64; ++it) {
        const int n = it * 64 + row;
        const f32x4* rp = memv + (size_t)n * (MM / 4) + sub * 4;
        float d = 0.f, q = 0.f;
        #pragma unroll
        for (int j = 0; j < 4; ++j) {
            f32x4 m = __builtin_nontemporal_load(rp + j);   // read-once stream
            m += EPS_ADD;
            d += m.x * kf[j].x + m.y * kf[j].y + m.z * kf[j].z + m.w * kf[j].w;
            q += m.x * m.x + m.y * m.y + m.z * m.z + m.w * m.w;
        }
        d += __shfl_xor(d, 1, 64); q += __shfl_xor(q, 1, 64);
        d += __shfl_xor(d, 2, 64); q += __shfl_xor(q, 2, 64);
        if (sub == 0) {
            const float e = __expf(binv * d / fmaxf(sqrtf(q), EPS_COS));
            sc[n] = e;
            lsum += e;
        }
    }
    const float Z  = block_reduce_sum(lsum, red);  // barriers also order sc writes
    const float gi = g_b / Z;
    const float gp = 1.0f - g_b;

    float* outb = out + (size_t)b * NN;

    if (S == 3) {
        // ---- fused interpolate + circular conv + sharpen (no LDS writeback) ----
        const float s0 = sreg[0], s1 = sreg[1], s2 = sreg[2];
        const f32x4* sc4 = (const f32x4*)sc;
        f32x4 vals[4];
        float lsum2 = 0.f;
        #pragma unroll
        for (int k = 0; k < 4; ++k) {
            const int idx  = tid + k * BLOCK;
            const int base = 4 * idx;
            const f32x4 e  = sc4[idx];
            const float eL = sc[(base + NN - 1) & (NN - 1)];
            const float eR = sc[(base + 4) & (NN - 1)];
            const float wgL = gi * eL  + gp * wpl[k];
            const float wg0 = gi * e.x + gp * wpv[k].x;
            const float wg1 = gi * e.y + gp * wpv[k].y;
            const float wg2 = gi * e.z + gp * wpv[k].z;
            const float wg3 = gi * e.w + gp * wpv[k].w;
            const float wgR = gi * eR  + gp * wpr[k];
            f32x4 h;
            h.x = s0 * wgL + s1 * wg0 + s2 * wg1;
            h.y = s0 * wg0 + s1 * wg1 + s2 * wg2;
            h.z = s0 * wg1 + s1 * wg2 + s2 * wg3;
            h.w = s0 * wg2 + s1 * wg3 + s2 * wgR;
            f32x4 v;
            v.x = __expf(gamma_b * __logf(h.x));
            v.y = __expf(gamma_b * __logf(h.y));
            v.z = __expf(gamma_b * __logf(h.z));
            v.w = __expf(gamma_b * __logf(h.w));
            vals[k] = v;
            lsum2 += v.x + v.y + v.z + v.w;
        }
        const float T   = block_reduce_sum(lsum2, red);
        const float inv = 1.0f / (T + EPS_ADD);
        f32x4* out4 = (f32x4*)outb;
        #pragma unroll
        for (int k = 0; k < 4; ++k) {
            __builtin_nontemporal_store(vals[k] * inv, out4 + tid + k * BLOCK);
        }
    } else {
        // ---- generic fallback (any S<=8): LDS w_g writeback + scalar conv ----
        const f32x4* wp4 = (const f32x4*)wpb;
        f32x4* sc4 = (f32x4*)sc;
        #pragma unroll
        for (int k = 0; k < 4; ++k) {
            const int idx = tid + k * BLOCK;
            f32x4 e = sc4[idx];
            const f32x4 w = wp4[idx];
            e = e * gi + w * gp;
            sc4[idx] = e;
        }
        __syncthreads();
        float vals[NN / BLOCK];
        float lsum2 = 0.f;
        #pragma unroll
        for (int k = 0; k < NN / BLOCK; ++k) {
            const int n = tid + k * BLOCK;
            float acc = 0.f;
            for (int j = 0; j < S; ++j) {
                const int idx = (n + j - 1 + NN) & (NN - 1);
                acc += sreg[j] * sc[idx];
            }
            const float v = __expf(gamma_b * __logf(acc));
            vals[k] = v;
            lsum2 += v;
        }
        const float T   = block_reduce_sum(lsum2, red);
        const float inv = 1.0f / (T + EPS_ADD);
        #pragma unroll
        for (int k = 0; k < NN / BLOCK; ++k) {
            outb[tid + k * BLOCK] = vals[k] * inv;
        }
    }
}

extern "C" void kernel_launch(void* const* d_in, const int* in_sizes, int n_in,
                              void* d_out, int out_size, void* d_ws, size_t ws_size,
                              hipStream_t stream) {
    const float* beta    = (const float*)d_in[0];
    const float* kappa   = (const float*)d_in[1];
    const float* gamma_p = (const float*)d_in[2];
    const float* g_p     = (const float*)d_in[3];
    const float* s_p     = (const float*)d_in[4];
    const float* w_prev  = (const float*)d_in[5];
    const float* memory  = (const float*)d_in[6];
    float* out = (float*)d_out;

    const int B = in_sizes[0];              // beta is (B,1)
    int S = in_sizes[4] / B;                // s is (B, INT_SHIFT)
    if (S > 8) S = 8;

    ntm_fused<<<B, BLOCK, 0, stream>>>(beta, kappa, gamma_p, g_p, s_p,
                                       w_prev, memory, out, S);
}

// Round 4
// 194.068 us; speedup vs baseline: 1.5293x; 1.5293x over previous
//
#include <hip/hip_runtime.h>
#include <math.h>

#define EPS_COS 1e-8f
#define EPS_ADD 1e-12f

constexpr int NN = 4096;   // N
constexpr int MM = 64;     // M
constexpr int BLOCK = 256;

using f32x4 = __attribute__((ext_vector_type(4))) float;

__device__ __forceinline__ float block_reduce_sum(float v, float* red) {
    #pragma unroll
    for (int o = 32; o > 0; o >>= 1) v += __shfl_xor(v, o, 64);
    const int wv = threadIdx.x >> 6;
    if ((threadIdx.x & 63) == 0) red[wv] = v;
    __syncthreads();
    float r = (red[0] + red[1]) + (red[2] + red[3]);
    __syncthreads();
    return r;
}

__global__ __launch_bounds__(BLOCK, 4) void ntm_fused(
    const float* __restrict__ beta,
    const float* __restrict__ kappa,
    const float* __restrict__ gamma_p,
    const float* __restrict__ g_p,
    const float* __restrict__ s_p,
    const float* __restrict__ w_prev,
    const float* __restrict__ memory,
    float* __restrict__ out,
    int S)
{
    const int b   = blockIdx.x;
    const int tid = threadIdx.x;
    const int sub = tid & 3;   // 4 threads per row, 16 floats each
    const int row = tid >> 2;  // 64 rows per sweep

    __shared__ float sc[NN];   // e = exp(beta*cos)
    __shared__ float red[4];

    // ---- early prefetch: w_prev fragment (consumed only after the stream) ----
    const float* wpb = w_prev + (size_t)b * NN;
    f32x4 wpv[4]; float wpl[4], wpr[4];
    #pragma unroll
    for (int k = 0; k < 4; ++k) {
        const int idx  = tid + k * BLOCK;
        const int base = 4 * idx;
        wpv[k] = ((const f32x4*)wpb)[idx];
        wpl[k] = wpb[(base + NN - 1) & (NN - 1)];
        wpr[k] = wpb[(base + 4) & (NN - 1)];
    }

    const float beta_b  = beta[b];
    const float g_b     = g_p[b];
    const float gamma_b = gamma_p[b];
    float sreg[8];
    #pragma unroll
    for (int j = 0; j < 8; ++j) sreg[j] = (j < S) ? s_p[(size_t)b * S + j] : 0.0f;

    // kappa fragment: 16 floats at element sub*16 (+eps), and k-norm
    const f32x4* kv = (const f32x4*)(kappa + (size_t)b * MM);
    f32x4 kf[4];
    float ksq = 0.f;
    #pragma unroll
    for (int j = 0; j < 4; ++j) {
        f32x4 t = kv[sub * 4 + j];
        t += EPS_ADD;
        kf[j] = t;
        ksq += t.x * t.x + t.y * t.y + t.z * t.z + t.w * t.w;
    }
    ksq += __shfl_xor(ksq, 1, 64);
    ksq += __shfl_xor(ksq, 2, 64);
    const float knorm = fmaxf(sqrtf(ksq), EPS_COS);
    const float binv  = beta_b / knorm;

    // ---- phase 1: e = exp(beta*cos) into LDS, accumulate softmax denom.
    // |beta*cos| < 1 so no max-subtraction is needed (no overflow possible).
    float lsum = 0.f;
    const f32x4* memv = (const f32x4*)(memory + (size_t)b * NN * MM);
    #pragma unroll 2
    for (int it = 0; it < NN / 64; ++it) {
        const int n = it * 64 + row;
        const f32x4* rp = memv + (size_t)n * (MM / 4) + sub * 4;
        float d = 0.f, q = 0.f;
        #pragma unroll
        for (int j = 0; j < 4; ++j) {
            f32x4 m = rp[j];
            m += EPS_ADD;
            d += m.x * kf[j].x + m.y * kf[j].y + m.z * kf[j].z + m.w * kf[j].w;
            q += m.x * m.x + m.y * m.y + m.z * m.z + m.w * m.w;
        }
        d += __shfl_xor(d, 1, 64); q += __shfl_xor(q, 1, 64);
        d += __shfl_xor(d, 2, 64); q += __shfl_xor(q, 2, 64);
        if (sub == 0) {
            const float e = __expf(binv * d / fmaxf(sqrtf(q), EPS_COS));
            sc[n] = e;
            lsum += e;
        }
    }
    const float Z  = block_reduce_sum(lsum, red);  // barriers also order sc writes
    const float gi = g_b / Z;
    const float gp = 1.0f - g_b;

    float* outb = out + (size_t)b * NN;

    if (S == 3) {
        // ---- fused interpolate + circular conv + sharpen (no LDS writeback) ----
        const float s0 = sreg[0], s1 = sreg[1], s2 = sreg[2];
        const f32x4* sc4 = (const f32x4*)sc;
        f32x4 vals[4];
        float lsum2 = 0.f;
        #pragma unroll
        for (int k = 0; k < 4; ++k) {
            const int idx  = tid + k * BLOCK;
            const int base = 4 * idx;
            const f32x4 e  = sc4[idx];
            const float eL = sc[(base + NN - 1) & (NN - 1)];
            const float eR = sc[(base + 4) & (NN - 1)];
            const float wgL = gi * eL  + gp * wpl[k];
            const float wg0 = gi * e.x + gp * wpv[k].x;
            const float wg1 = gi * e.y + gp * wpv[k].y;
            const float wg2 = gi * e.z + gp * wpv[k].z;
            const float wg3 = gi * e.w + gp * wpv[k].w;
            const float wgR = gi * eR  + gp * wpr[k];
            f32x4 h;
            h.x = s0 * wgL + s1 * wg0 + s2 * wg1;
            h.y = s0 * wg0 + s1 * wg1 + s2 * wg2;
            h.z = s0 * wg1 + s1 * wg2 + s2 * wg3;
            h.w = s0 * wg2 + s1 * wg3 + s2 * wgR;
            f32x4 v;
            v.x = __expf(gamma_b * __logf(h.x));
            v.y = __expf(gamma_b * __logf(h.y));
            v.z = __expf(gamma_b * __logf(h.z));
            v.w = __expf(gamma_b * __logf(h.w));
            vals[k] = v;
            lsum2 += v.x + v.y + v.z + v.w;
        }
        const float T   = block_reduce_sum(lsum2, red);
        const float inv = 1.0f / (T + EPS_ADD);
        f32x4* out4 = (f32x4*)outb;
        #pragma unroll
        for (int k = 0; k < 4; ++k) {
            out4[tid + k * BLOCK] = vals[k] * inv;
        }
    } else {
        // ---- generic fallback (any S<=8): LDS w_g writeback + scalar conv ----
        const f32x4* wp4 = (const f32x4*)wpb;
        f32x4* sc4 = (f32x4*)sc;
        #pragma unroll
        for (int k = 0; k < 4; ++k) {
            const int idx = tid + k * BLOCK;
            f32x4 e = sc4[idx];
            const f32x4 w = wp4[idx];
            e = e * gi + w * gp;
            sc4[idx] = e;
        }
        __syncthreads();
        float vals[NN / BLOCK];
        float lsum2 = 0.f;
        #pragma unroll
        for (int k = 0; k < NN / BLOCK; ++k) {
            const int n = tid + k * BLOCK;
            float acc = 0.f;
            for (int j = 0; j < S; ++j) {
                const int idx = (n + j - 1 + NN) & (NN - 1);
                acc += sreg[j] * sc[idx];
            }
            const float v = __expf(gamma_b * __logf(acc));
            vals[k] = v;
            lsum2 += v;
        }
        const float T   = block_reduce_sum(lsum2, red);
        const float inv = 1.0f / (T + EPS_ADD);
        #pragma unroll
        for (int k = 0; k < NN / BLOCK; ++k) {
            outb[tid + k * BLOCK] = vals[k] * inv;
        }
    }
}

extern "C" void kernel_launch(void* const* d_in, const int* in_sizes, int n_in,
                              void* d_out, int out_size, void* d_ws, size_t ws_size,
                              hipStream_t stream) {
    const float* beta    = (const float*)d_in[0];
    const float* kappa   = (const float*)d_in[1];
    const float* gamma_p = (const float*)d_in[2];
    const float* g_p     = (const float*)d_in[3];
    const float* s_p     = (const float*)d_in[4];
    const float* w_prev  = (const float*)d_in[5];
    const float* memory  = (const float*)d_in[6];
    float* out = (float*)d_out;

    const int B = in_sizes[0];              // beta is (B,1)
    int S = in_sizes[4] / B;                // s is (B, INT_SHIFT)
    if (S > 8) S = 8;

    ntm_fused<<<B, BLOCK, 0, stream>>>(beta, kappa, gamma_p, g_p, s_p,
                                       w_prev, memory, out, S);
}